// Round 1
// baseline (102.448 us; speedup 1.0000x reference)
//
#include <hip/hip_runtime.h>

// EdgeCondGCNNTF: B=2,T=32,N=64,FIN=64,FOUT=64,EDIM=16.
// Factorized: agg = H_b @ Z[b,t],  Z[b,t,j,e,:] = xn[b,t,j,:] @ W2_e,
// rank-1 eb2 term via column-sum closed form, plus node_lin GEMM.
// v4: SINGLE kernel, ZERO workspace use (hypothesis: the 256MiB ws poison
//     fill at ~40us/iter leaves the timed path if ws is untouched; also
//     removes one launch+drain).
//     - W2t/NWt slices (this block's o-half) transposed-loaded to LDS
//       during the norm phase (ew2 is L2-resident; 128KB/block re-read).
//     - H never materialized: per-lane A-fragments computed on the fly
//       from 16 hoisted adj registers, gelu via 5-term erf Taylor
//       (|v|<=0.6 guaranteed by xavier bound; guarded erff fallback).
//       VALU overlaps phase-1 MFMAs.
//     - norm / eb2 closed form / node_lin / exact-erf epilogue unchanged.

#define LSTR 72  // LDS f16 row stride: 144B (16B-aligned rows, conflicts spread across quarter-waves)
#define XSTR 68  // LDS f32 row stride for raw x
#define CE 4     // e-chunk depth

typedef unsigned short u16;
typedef _Float16 f16;
typedef _Float16 f16x8 __attribute__((ext_vector_type(8)));
typedef _Float16 f16x4 __attribute__((ext_vector_type(4)));
typedef float f32x4 __attribute__((ext_vector_type(4)));

__device__ __forceinline__ float bf2f(u16 u) {
    union { unsigned int i; float f; } c; c.i = ((unsigned int)u) << 16; return c.f;
}
__device__ __forceinline__ u16 f2bf(float f) {
    union { float f; unsigned int i; } c; c.f = f;
    unsigned int r = c.i + 0x7FFFu + ((c.i >> 16) & 1u);
    return (u16)(r >> 16);
}
__device__ __forceinline__ float gelu_exact(float v) {
    return 0.5f * v * (1.0f + erff(v * 0.70710678118654752440f));
}
// Fast exact-GELU for the edge-net range: |v| <= ~0.6 (xavier limit 0.594 * adj in [0,1), eb1=0).
// erf(v/sqrt2) = 0.7978845608*v*(1 - z2/3 + z2^2/10 - z2^3/42 + z2^4/216), z2 = v^2/2.
// abs err < 2e-5 at |v|=1 (we're at <=0.6); guarded erff fallback for safety.
__device__ __forceinline__ f16 gelu_small(float v) {
    float g;
    if (__builtin_expect(fabsf(v) <= 1.0f, 1)) {
        float z2 = 0.5f * v * v;
        float p = 1.0f + z2 * (-0.33333333333333f
                + z2 * (0.1f + z2 * (-0.02380952380952f + z2 * 0.00462962962963f)));
        g = 0.5f * v * (1.0f + 0.79788456080287f * v * p);
    } else {
        g = gelu_exact(v);
    }
    return (f16)g;
}
__device__ __forceinline__ float loadf(const void* p, int i, bool bf) {
    return bf ? bf2f(((const u16*)p)[i]) : ((const float*)p)[i];
}
// Sniff x's storage dtype (bf16 vs fp32). Even-index u16s: bf16 -> sane exponents.
__device__ __forceinline__ int detect_bf16(const void* xp) {
    const u16* u = (const u16*)xp;
    int sane = 0;
    for (int k = 0; k < 64; ++k) {
        int e = (u[k * 2] >> 7) & 0xFF;
        sane += (e >= 100 && e <= 150);
    }
    return sane >= 40;
}

// ---- Single fused kernel: 128 blocks = (b,t) x o-half; 256 threads (4 waves).
__global__ __launch_bounds__(256) void fused_all(
    const void* __restrict__ x, const void* __restrict__ adj,
    const void* __restrict__ ew1, const void* __restrict__ eb1,
    const void* __restrict__ ew2, const void* __restrict__ eb2,
    const void* __restrict__ nw, const void* __restrict__ nb,
    const void* __restrict__ gw, const void* __restrict__ gb,
    const void* __restrict__ gms, void* __restrict__ out)
{
    __shared__ float xraw[64 * XSTR];          // 17408 B
    __shared__ f16 xn_lds[64 * LSTR];          //  9216 B
    __shared__ f16 zt_lds[CE * 32 * LSTR];     // 18432 B
    __shared__ f16 w2s[(16 * 32 + 32) * LSTR]; // 78336 B: [e 0..15][o_local 0..31][f], row 512+ = nw
    __shared__ float red1[256];
    __shared__ float red2[256];
    __shared__ float af[64], cf[64], Sv[64], t2o[64];
    __shared__ float ew1s[16], eb1s[16];
    __shared__ int s_bf;

    const int tid  = threadIdx.x;
    const int blk  = blockIdx.x;        // 0..127
    const int bt   = blk >> 1;          // 0..63
    const int half = blk & 1;           // o-half
    const int b    = bt >> 5;
    const int lane = tid & 63;
    const int wave = tid >> 6;          // 4 waves; wave = node row-tile
    const int ln   = lane & 15;
    const int q    = lane >> 4;
    const int row  = tid >> 2;          // staging: 64 rows, 4 threads/row
    const int colb = (tid & 3) << 4;    // 0,16,32,48

    if (tid == 0) s_bf = detect_bf16(x);
    __syncthreads();
    const bool bf = (s_bf != 0);
    if (tid < 16) { ew1s[tid] = loadf(ew1, tid, bf); eb1s[tid] = loadf(eb1, tid, bf); }

    // hoist this lane's 16 adj values (H A-fragment source): row i = wave*16+ln,
    // cols q*8..q*8+7 and 32+q*8..32+q*8+7. One-time, L2-resident.
    float adjv[16];
    {
        int basea = (b << 12) + ((wave * 16 + ln) << 6);
        if (bf) {
            const u16* ap = (const u16*)adj + basea;
            #pragma unroll
            for (int k = 0; k < 8; ++k) {
                adjv[k]     = bf2f(ap[q * 8 + k]);
                adjv[8 + k] = bf2f(ap[32 + q * 8 + k]);
            }
        } else {
            const float* ap = (const float*)adj + basea;
            #pragma unroll
            for (int k = 0; k < 8; ++k) {
                adjv[k]     = ap[q * 8 + k];
                adjv[8 + k] = ap[32 + q * 8 + k];
            }
        }
    }

    // stage raw x[b,t] into xraw (fp32), coalesced vector loads per mode
    {
        int base = (bt << 12) + (row << 6) + colb;
        if (bf) {
            const uint4* src = (const uint4*)((const u16*)x + base);
            uint4 v0 = src[0], v1 = src[1];
            const u16* p0 = (const u16*)&v0;
            const u16* p1 = (const u16*)&v1;
            #pragma unroll
            for (int k = 0; k < 8; ++k) {
                xraw[row * XSTR + colb + k]     = bf2f(p0[k]);
                xraw[row * XSTR + colb + 8 + k] = bf2f(p1[k]);
            }
        } else {
            const float4* src = (const float4*)((const float*)x + base);
            #pragma unroll
            for (int k = 0; k < 4; ++k) {
                float4 v = src[k];
                xraw[row * XSTR + colb + 4 * k]     = v.x;
                xraw[row * XSTR + colb + 4 * k + 1] = v.y;
                xraw[row * XSTR + colb + 4 * k + 2] = v.z;
                xraw[row * XSTR + colb + 4 * k + 3] = v.w;
            }
        }
    }
    __syncthreads();
    // per-feature mean / E[x^2] over the 64 nodes (column reduction, 4 partials)
    {
        int f = tid & 63, part = tid >> 6;
        float s1 = 0.f, s2 = 0.f;
        #pragma unroll
        for (int r = 0; r < 16; ++r) {
            float v = xraw[(part * 16 + r) * XSTR + f];
            s1 += v; s2 += v * v;
        }
        red1[part * 64 + f] = s1; red2[part * 64 + f] = s2;
    }
    __syncthreads();
    if (tid < 64) {
        float s1 = red1[tid] + red1[64 + tid] + red1[128 + tid] + red1[192 + tid];
        float s2 = red2[tid] + red2[64 + tid] + red2[128 + tid] + red2[192 + tid];
        float mean = s1 * 0.015625f;
        float var  = s2 * 0.015625f - mean * mean;   // ddof=0
        float inv  = rsqrtf(var + 1e-5f);
        float gwf = loadf(gw, tid, bf), gbf = loadf(gb, tid, bf), g = loadf(gms, 0, bf);
        float a = inv * gwf;
        af[tid] = a;
        cf[tid] = gbf - mean * g * a;
        // S[f] = sum_j xn[j,f] = 64*(mean*(1-gms)*inv*gw + gb)  (closed form)
        Sv[tid] = 64.f * (mean * (1.f - g) * a + gbf);
    }
    __syncthreads();
    // normalize: xraw -> xn_lds as f16
    {
        #pragma unroll
        for (int k = 0; k < 16; ++k) {
            int col = colb + k;
            xn_lds[row * LSTR + col] = (f16)(xraw[row * XSTR + col] * af[col] + cf[col]);
        }
    }
    // W2t/NWt slice for this o-half -> LDS (transpose: f becomes contiguous).
    // thread = (o_local = tid&31, f-group = tid>>5); L2-resident re-read.
    {
        int olc = tid & 31, fg = tid >> 5;
        #pragma unroll 4
        for (int e = 0; e < 16; ++e) {
            f16x8 tmp;
            #pragma unroll
            for (int k = 0; k < 8; ++k)
                tmp[k] = (f16)loadf(ew2, (e << 12) + ((fg * 8 + k) << 6) + (half << 5) + olc, bf);
            *(f16x8*)&w2s[(e * 32 + olc) * LSTR + fg * 8] = tmp;
        }
        f16x8 tmp;
        #pragma unroll
        for (int k = 0; k < 8; ++k)
            tmp[k] = (f16)loadf(nw, ((fg * 8 + k) << 6) + (half << 5) + olc, bf);
        *(f16x8*)&w2s[(512 + olc) * LSTR + fg * 8] = tmp;
    }
    // t2[o] = sum_f S[f]*eb2[f,o] partials (the eb2 part of edge_w)
    {
        int o = tid & 63, part = tid >> 6;
        float s = 0.f;
        #pragma unroll
        for (int r = 0; r < 16; ++r) {
            int f = part * 16 + r;
            s += Sv[f] * loadf(eb2, (f << 6) + o, bf);
        }
        red1[part * 64 + o] = s;
    }
    __syncthreads();
    if (tid < 64)
        t2o[tid] = red1[tid] + red1[64 + tid] + red1[128 + tid] + red1[192 + tid]
                 + loadf(nb, tid, bf);
    __syncthreads();   // xn_lds + w2s complete for all waves

    // hoisted xn A-fragments (this wave's node row-tile, full K=f)
    f16x8 xa0 = *(const f16x8*)&xn_lds[(wave * 16 + ln) * LSTR + q * 8];
    f16x8 xa1 = *(const f16x8*)&xn_lds[(wave * 16 + ln) * LSTR + 32 + q * 8];

    // dual accumulation chains per o-tile (kc parity) for ILP
    f32x4 accA[2], accB[2];
    #pragma unroll
    for (int i2 = 0; i2 < 2; ++i2) {
        accA[i2] = (f32x4){0.f, 0.f, 0.f, 0.f};
        accB[i2] = (f32x4){0.f, 0.f, 0.f, 0.f};
    }

    for (int ec = 0; ec < 16 / CE; ++ec) {
        __syncthreads();   // zt reuse: prior readers done
        // phase 1: Z_e = xn @ W2_e for this chunk (B-frags from w2s LDS);
        // interleaved: compute this chunk's H A-fragments in-register
        // (VALU overlaps the MFMAs — separate pipes).
        f16x8 ha0c[CE], ha1c[CE];
        #pragma unroll
        for (int el = 0; el < CE; ++el) {
            int e = ec * CE + el;
            #pragma unroll
            for (int tn = 0; tn < 2; ++tn) {
                const f16* wrow = &w2s[(e * 32 + tn * 16 + ln) * LSTR];
                f16x8 b0 = *(const f16x8*)(wrow + q * 8);
                f16x8 b1 = *(const f16x8*)(wrow + 32 + q * 8);
                f32x4 z = {0.f, 0.f, 0.f, 0.f};
                z = __builtin_amdgcn_mfma_f32_16x16x32_f16(xa0, b0, z, 0, 0, 0);
                z = __builtin_amdgcn_mfma_f32_16x16x32_f16(xa1, b1, z, 0, 0, 0);
                // C/D: row(j)=q*4+r, col(o_local)=tn*16+ln -> zt[el][o_local][j]
                f16x4 p;
                #pragma unroll
                for (int r = 0; r < 4; ++r) p[r] = (f16)z[r];
                *(f16x4*)&zt_lds[(el * 32 + tn * 16 + ln) * LSTR + wave * 16 + q * 4] = p;
            }
            float w1 = ew1s[e], b1e = eb1s[e];
            #pragma unroll
            for (int k = 0; k < 8; ++k) {
                ha0c[el][k] = gelu_small(adjv[k] * w1 + b1e);
                ha1c[el][k] = gelu_small(adjv[8 + k] * w1 + b1e);
            }
        }
        __syncthreads();
        // phase 2: acc += H_be @ Z_e; A-frags from registers (no H anywhere).
        #pragma unroll
        for (int el = 0; el < CE; ++el) {
            #pragma unroll
            for (int tn = 0; tn < 2; ++tn) {
                f16x8 zb0 = *(const f16x8*)&zt_lds[(el * 32 + tn * 16 + ln) * LSTR + q * 8];
                f16x8 zb1 = *(const f16x8*)&zt_lds[(el * 32 + tn * 16 + ln) * LSTR + 32 + q * 8];
                accA[tn] = __builtin_amdgcn_mfma_f32_16x16x32_f16(ha0c[el], zb0, accA[tn], 0, 0, 0);
                accB[tn] = __builtin_amdgcn_mfma_f32_16x16x32_f16(ha1c[el], zb1, accB[tn], 0, 0, 0);
            }
        }
    }
    // node_lin: acc += xn @ nw (B-frags from w2s row 512+, this o-half)
    #pragma unroll
    for (int tn = 0; tn < 2; ++tn) {
        const f16* nrow = &w2s[(512 + tn * 16 + ln) * LSTR];
        f16x8 b0 = *(const f16x8*)(nrow + q * 8);
        f16x8 b1 = *(const f16x8*)(nrow + 32 + q * 8);
        accA[tn] = __builtin_amdgcn_mfma_f32_16x16x32_f16(xa0, b0, accA[tn], 0, 0, 0);
        accB[tn] = __builtin_amdgcn_mfma_f32_16x16x32_f16(xa1, b1, accB[tn], 0, 0, 0);
    }
    // epilogue: merge chains, + t2[o] (nb folded in), exact GELU, store per mode
    {
        if (bf) {
            u16* ob = (u16*)out + (bt << 12);
            #pragma unroll
            for (int tn = 0; tn < 2; ++tn) {
                int o = half * 32 + tn * 16 + ln;
                float add = t2o[o];
                #pragma unroll
                for (int r = 0; r < 4; ++r) {
                    int i = wave * 16 + q * 4 + r;
                    ob[(i << 6) + o] = f2bf(gelu_exact(accA[tn][r] + accB[tn][r] + add));
                }
            }
        } else {
            float* ob = (float*)out + (bt << 12);
            #pragma unroll
            for (int tn = 0; tn < 2; ++tn) {
                int o = half * 32 + tn * 16 + ln;
                float add = t2o[o];
                #pragma unroll
                for (int r = 0; r < 4; ++r) {
                    int i = wave * 16 + q * 4 + r;
                    ob[(i << 6) + o] = gelu_exact(accA[tn][r] + accB[tn][r] + add);
                }
            }
        }
    }
}

extern "C" void kernel_launch(void* const* d_in, const int* in_sizes, int n_in,
                              void* d_out, int out_size, void* d_ws, size_t ws_size,
                              hipStream_t stream) {
    const void* x   = d_in[0];
    const void* adj = d_in[1];
    const void* ew1 = d_in[2];
    const void* eb1 = d_in[3];
    const void* ew2 = d_in[4];
    const void* eb2 = d_in[5];
    const void* nw  = d_in[6];
    const void* nb  = d_in[7];
    const void* gw  = d_in[8];
    const void* gb  = d_in[9];
    const void* gms = d_in[10];
    (void)d_ws; (void)ws_size;   // deliberately unused: keep the 256MiB ws
                                 // poison fill out of the timed path

    fused_all<<<128, 256, 0, stream>>>(x, adj, ew1, eb1, ew2, eb2, nw, nb,
                                       gw, gb, gms, d_out);
}

// Round 2
// 91.068 us; speedup vs baseline: 1.1250x; 1.1250x over previous
//
#include <hip/hip_runtime.h>

// EdgeCondGCNNTF: B=2,T=32,N=64,FIN=64,FOUT=64,EDIM=16.
// Factorized: agg = H_b @ Z[b,t],  Z[b,t,j,e,:] = xn[b,t,j,:] @ W2_e,
// rank-1 eb2 term via column-sum closed form, plus node_lin GEMM.
// v5: back to two kernels (v4's per-block ew2 transpose was ~14us of
//     stride-64 scalar loads; the 784-block precomp does it coalesced).
//     fused_main restructured for latency, not throughput:
//     - single-GEMM view: agg = Hbig(64x1024) @ Zbig(1024x32) over the
//       combined (e,j) K-index. ALL Z_e materialized to LDS first (16-deep
//       zt, 36KB), ONE barrier, then an unbroken 34-MFMA K-loop.
//       Barriers: 13 -> 5.
//     - 256 blocks = (b,t) x o-QUARTER: every CU gets a block, per-block
//       critical path halves.
//     - 4 accumulator chains (kk&3, static unroll) for dep-chain ILP at
//       ~1 wave/SIMD occupancy.
//     - per-thread bf16-sniff (no barrier #0).

#define LSTR 72  // LDS f16 row stride: 144B = 16B*9 (aligned, odd granule -> spread banks)
#define XSTR 68  // LDS f32 row stride for raw x

typedef unsigned short u16;
typedef _Float16 f16;
typedef _Float16 f16x8 __attribute__((ext_vector_type(8)));
typedef _Float16 f16x4 __attribute__((ext_vector_type(4)));
typedef float f32x4 __attribute__((ext_vector_type(4)));

__device__ __forceinline__ float bf2f(u16 u) {
    union { unsigned int i; float f; } c; c.i = ((unsigned int)u) << 16; return c.f;
}
__device__ __forceinline__ u16 f2bf(float f) {
    union { float f; unsigned int i; } c; c.f = f;
    unsigned int r = c.i + 0x7FFFu + ((c.i >> 16) & 1u);
    return (u16)(r >> 16);
}
__device__ __forceinline__ float gelu_exact(float v) {
    return 0.5f * v * (1.0f + erff(v * 0.70710678118654752440f));
}
__device__ __forceinline__ float loadf(const void* p, int i, bool bf) {
    return bf ? bf2f(((const u16*)p)[i]) : ((const float*)p)[i];
}
// Sniff x's storage dtype (bf16 vs fp32). Even-index u16s: bf16 -> sane exponents.
// Per-thread (same 128B for everyone -> L1 broadcast); no barrier needed.
__device__ __forceinline__ int detect_bf16(const void* xp) {
    const u16* u = (const u16*)xp;
    int sane = 0;
    #pragma unroll
    for (int k = 0; k < 64; ++k) {
        int e = (u[k * 2] >> 7) & 0xFF;
        sane += (e >= 100 && e <= 150);
    }
    return sane >= 40;
}

// ---- Kernel A: h = gelu(adj*ew1+eb1) -> H[b][e][i][j]; transpose ew2 -> W2t[e][o][f];
//      transpose nw -> NWt[o][f]. All f16 into workspace. 784*256 = 200704 items exactly.
__global__ __launch_bounds__(256) void precomp(
    const void* __restrict__ adj, const void* __restrict__ ew1, const void* __restrict__ eb1,
    const void* __restrict__ ew2, const void* __restrict__ nw, const void* __restrict__ x,
    f16* __restrict__ H, f16* __restrict__ W2t, f16* __restrict__ NWt)
{
    const bool bf = detect_bf16(x) != 0;

    int idx = blockIdx.x * 256 + threadIdx.x;
    if (idx < 131072) {                       // B*EDIM*N*N
        int b = idx >> 16, rem = idx & 65535, e = rem >> 12, ij = rem & 4095;
        float a = loadf(adj, (b << 12) + ij, bf);
        float v = a * loadf(ew1, e, bf) + loadf(eb1, e, bf);
        H[idx] = (f16)gelu_exact(v);
    } else if (idx < 196608) {                // EDIM*FOUT*FIN
        int k = idx - 131072, e = k >> 12, of = k & 4095, o = of >> 6, f = of & 63;
        W2t[k] = (f16)loadf(ew2, (e << 12) + (f << 6) + o, bf);
    } else if (idx < 200704) {                // FOUT*FIN
        int k = idx - 196608, o = k >> 6, f = k & 63;
        NWt[k] = (f16)loadf(nw, (f << 6) + o, bf);
    }
}

// ---- Kernel B: 256 blocks = (b,t) x o-quarter. Norm in LDS; phase 1 fills
//      the full 16-deep Z; one barrier; phase 2 = single K=1024(+64) MFMA chain.
__global__ __launch_bounds__(256) void fused_main(
    const void* __restrict__ x, const void* __restrict__ eb2, const void* __restrict__ nb,
    const void* __restrict__ gw, const void* __restrict__ gb, const void* __restrict__ gms,
    const f16* __restrict__ H, const f16* __restrict__ W2t, const f16* __restrict__ NWt,
    void* __restrict__ out)
{
    __shared__ float xraw[64 * XSTR];        // 17408 B
    __shared__ f16 xn_lds[64 * LSTR];        //  9216 B
    __shared__ f16 zt_lds[16 * 16 * LSTR];   // 36864 B: row = e*16 + o_local, col = j
    __shared__ float red1[256];
    __shared__ float red2[256];
    __shared__ float af[64], cf[64], Sv[64], t2o[64];

    const int tid  = threadIdx.x;
    const int blk  = blockIdx.x;        // 0..255
    const int bt   = blk >> 2;          // 0..63
    const int quar = blk & 3;           // o-quarter
    const int b    = bt >> 5;
    const int lane = tid & 63;
    const int wave = tid >> 6;          // 4 waves; wave = node row-tile
    const int ln   = lane & 15;
    const int q    = lane >> 4;
    const int row  = tid >> 2;          // staging: 64 rows, 4 threads/row
    const int colb = (tid & 3) << 4;    // 0,16,32,48

    const bool bf = detect_bf16(x) != 0;

    // stage raw x[b,t] into xraw (fp32), coalesced vector loads per mode
    {
        int base = (bt << 12) + (row << 6) + colb;
        if (bf) {
            const uint4* src = (const uint4*)((const u16*)x + base);
            uint4 v0 = src[0], v1 = src[1];
            const u16* p0 = (const u16*)&v0;
            const u16* p1 = (const u16*)&v1;
            #pragma unroll
            for (int k = 0; k < 8; ++k) {
                xraw[row * XSTR + colb + k]     = bf2f(p0[k]);
                xraw[row * XSTR + colb + 8 + k] = bf2f(p1[k]);
            }
        } else {
            const float4* src = (const float4*)((const float*)x + base);
            #pragma unroll
            for (int k = 0; k < 4; ++k) {
                float4 v = src[k];
                xraw[row * XSTR + colb + 4 * k]     = v.x;
                xraw[row * XSTR + colb + 4 * k + 1] = v.y;
                xraw[row * XSTR + colb + 4 * k + 2] = v.z;
                xraw[row * XSTR + colb + 4 * k + 3] = v.w;
            }
        }
    }
    __syncthreads();                                   // (1)
    // per-feature mean / E[x^2] over the 64 nodes (column reduction, 4 partials)
    {
        int f = tid & 63, part = tid >> 6;
        float s1 = 0.f, s2 = 0.f;
        #pragma unroll
        for (int r = 0; r < 16; ++r) {
            float v = xraw[(part * 16 + r) * XSTR + f];
            s1 += v; s2 += v * v;
        }
        red1[part * 64 + f] = s1; red2[part * 64 + f] = s2;
    }
    __syncthreads();                                   // (2)
    if (tid < 64) {
        float s1 = red1[tid] + red1[64 + tid] + red1[128 + tid] + red1[192 + tid];
        float s2 = red2[tid] + red2[64 + tid] + red2[128 + tid] + red2[192 + tid];
        float mean = s1 * 0.015625f;
        float var  = s2 * 0.015625f - mean * mean;   // ddof=0
        float inv  = rsqrtf(var + 1e-5f);
        float gwf = loadf(gw, tid, bf), gbf = loadf(gb, tid, bf), g = loadf(gms, 0, bf);
        float a = inv * gwf;
        af[tid] = a;
        cf[tid] = gbf - mean * g * a;
        // S[f] = sum_j xn[j,f] = 64*(mean*(1-gms)*inv*gw + gb)  (closed form)
        Sv[tid] = 64.f * (mean * (1.f - g) * a + gbf);
    }
    __syncthreads();                                   // (3)
    // normalize: xraw -> xn_lds as f16
    {
        #pragma unroll
        for (int k = 0; k < 16; ++k) {
            int col = colb + k;
            xn_lds[row * LSTR + col] = (f16)(xraw[row * XSTR + col] * af[col] + cf[col]);
        }
    }
    // t2[o] = sum_f S[f]*eb2[f,o] partials (the eb2 part of edge_w)
    {
        int o = tid & 63, part = tid >> 6;
        float s = 0.f;
        #pragma unroll
        for (int r = 0; r < 16; ++r) {
            int f = part * 16 + r;
            s += Sv[f] * loadf(eb2, (f << 6) + o, bf);
        }
        red1[part * 64 + o] = s;
    }
    __syncthreads();                                   // (4)
    if (tid < 64)
        t2o[tid] = red1[tid] + red1[64 + tid] + red1[128 + tid] + red1[192 + tid]
                 + loadf(nb, tid, bf);

    // hoisted xn A-fragments (this wave's node row-tile, full K=f)
    f16x8 xa0 = *(const f16x8*)&xn_lds[(wave * 16 + ln) * LSTR + q * 8];
    f16x8 xa1 = *(const f16x8*)&xn_lds[(wave * 16 + ln) * LSTR + 32 + q * 8];

    // ---- phase 1: Z_e = xn @ W2_e for ALL 16 e (this o-quarter, 16 cols).
    //      B-frags direct from global W2t (L2/L1-resident). No barriers inside.
    #pragma unroll
    for (int e = 0; e < 16; ++e) {
        const f16* wrow = W2t + (((e << 6) + (quar << 4) + ln) << 6);
        f16x8 b0 = *(const f16x8*)(wrow + q * 8);
        f16x8 b1 = *(const f16x8*)(wrow + 32 + q * 8);
        f32x4 z = {0.f, 0.f, 0.f, 0.f};
        z = __builtin_amdgcn_mfma_f32_16x16x32_f16(xa0, b0, z, 0, 0, 0);
        z = __builtin_amdgcn_mfma_f32_16x16x32_f16(xa1, b1, z, 0, 0, 0);
        // C/D: row(j-in-tile)=q*4+r, col(o_local)=ln -> zt[e*16+o_local][j]
        f16x4 p;
        #pragma unroll
        for (int r = 0; r < 4; ++r) p[r] = (f16)z[r];
        *(f16x4*)&zt_lds[((e << 4) + ln) * LSTR + wave * 16 + q * 4] = p;
    }
    __syncthreads();                                   // (5) — the only GEMM barrier

    // ---- phase 2: acc += Hbig @ Zbig, K = (e,j) = 1024, in one chain.
    //      4 accumulator chains over kk&3 (statically unrolled).
    f32x4 acc0 = {0.f,0.f,0.f,0.f}, acc1 = {0.f,0.f,0.f,0.f};
    f32x4 acc2 = {0.f,0.f,0.f,0.f}, acc3 = {0.f,0.f,0.f,0.f};
    const f16* hbase = H + ((b * 16) << 12) + ((wave * 16 + ln) << 6) + q * 8;
    #pragma unroll
    for (int kk = 0; kk < 32; ++kk) {
        const int e = kk >> 1, jh = kk & 1;
        f16x8 ha = *(const f16x8*)(hbase + (e << 12) + jh * 32);
        f16x8 zb = *(const f16x8*)&zt_lds[((e << 4) + ln) * LSTR + jh * 32 + q * 8];
        switch (kk & 3) {
            case 0: acc0 = __builtin_amdgcn_mfma_f32_16x16x32_f16(ha, zb, acc0, 0, 0, 0); break;
            case 1: acc1 = __builtin_amdgcn_mfma_f32_16x16x32_f16(ha, zb, acc1, 0, 0, 0); break;
            case 2: acc2 = __builtin_amdgcn_mfma_f32_16x16x32_f16(ha, zb, acc2, 0, 0, 0); break;
            default: acc3 = __builtin_amdgcn_mfma_f32_16x16x32_f16(ha, zb, acc3, 0, 0, 0); break;
        }
    }
    // node_lin: acc += xn @ nw (B-frags direct from global NWt, this o-quarter)
    {
        const f16* nrow = NWt + (((quar << 4) + ln) << 6);
        f16x8 b0 = *(const f16x8*)(nrow + q * 8);
        f16x8 b1 = *(const f16x8*)(nrow + 32 + q * 8);
        acc0 = __builtin_amdgcn_mfma_f32_16x16x32_f16(xa0, b0, acc0, 0, 0, 0);
        acc1 = __builtin_amdgcn_mfma_f32_16x16x32_f16(xa1, b1, acc1, 0, 0, 0);
    }
    // epilogue: merge chains, + t2[o] (nb folded in), exact GELU, store per mode
    {
        const int o = (quar << 4) + ln;
        const float add = t2o[o];
        if (bf) {
            u16* ob = (u16*)out + (bt << 12);
            #pragma unroll
            for (int r = 0; r < 4; ++r) {
                int i = wave * 16 + q * 4 + r;
                float v = acc0[r] + acc1[r] + acc2[r] + acc3[r] + add;
                ob[(i << 6) + o] = f2bf(gelu_exact(v));
            }
        } else {
            float* ob = (float*)out + (bt << 12);
            #pragma unroll
            for (int r = 0; r < 4; ++r) {
                int i = wave * 16 + q * 4 + r;
                float v = acc0[r] + acc1[r] + acc2[r] + acc3[r] + add;
                ob[(i << 6) + o] = gelu_exact(v);
            }
        }
    }
}

extern "C" void kernel_launch(void* const* d_in, const int* in_sizes, int n_in,
                              void* d_out, int out_size, void* d_ws, size_t ws_size,
                              hipStream_t stream) {
    const void* x   = d_in[0];
    const void* adj = d_in[1];
    const void* ew1 = d_in[2];
    const void* eb1 = d_in[3];
    const void* ew2 = d_in[4];
    const void* eb2 = d_in[5];
    const void* nw  = d_in[6];
    const void* nb  = d_in[7];
    const void* gw  = d_in[8];
    const void* gb  = d_in[9];
    const void* gms = d_in[10];

    f16* H   = (f16*)d_ws;            // 131072 f16
    f16* W2t = H + 131072;            // 65536 f16
    f16* NWt = W2t + 65536;           // 4096 f16  (total 401408 B of ws)

    precomp<<<784, 256, 0, stream>>>(adj, ew1, eb1, ew2, nw, x, H, W2t, NWt);
    fused_main<<<256, 256, 0, stream>>>(x, eb2, nb, gw, gb, gms, H, W2t, NWt, d_out);
}